// Round 12
// baseline (4061.743 us; speedup 1.0000x reference)
//
#include <hip/hip_runtime.h>
#include <hip/hip_bf16.h>

#define NN 20000
#define NE 640000

constexpr float INV_AVG = 0.17677669529663687f;  // 1/sqrt(32)
constexpr float SQRT3   = 1.7320508075688772f;
constexpr float BPREF   = 0.6324555320336759f;   // sqrt(2/5)
constexpr float PI_F    = 3.14159265358979323846f;

__device__ __forceinline__ float sigmoidf_(float x) { return 1.0f / (1.0f + __expf(-x)); }

// ---------------- embedding ----------------
__global__ __launch_bounds__(256) void k_embed(const float* __restrict__ attrs,
                                               const float* __restrict__ W,
                                               float* __restrict__ s)
{
    int t = blockIdx.x * 256 + threadIdx.x;     // t = n*32 + f
    int n = t >> 5, f = t & 31;
    const float* ar = attrs + n * 64;
    float acc = 0.f;
    #pragma unroll
    for (int a = 0; a < 64; ++a) acc += ar[a] * W[a * 32 + f];
    s[t] = acc;
}

// ---------------- CSR build ----------------
__global__ __launch_bounds__(256) void k_count(const int* __restrict__ ei, int* __restrict__ deg)
{
    int e = blockIdx.x * 256 + threadIdx.x;
    atomicAdd(&deg[ei[NE + e]], 1);
}

__global__ __launch_bounds__(256) void k_scan(const int* __restrict__ deg,
                                              int* __restrict__ base,
                                              int* __restrict__ cursor)
{
    __shared__ int part[256];
    int t = threadIdx.x;
    int start = t * 80;
    int s = 0;
    for (int i = 0; i < 80; ++i) { int n = start + i; if (n < NN) s += deg[n]; }
    part[t] = s;
    __syncthreads();
    for (int off = 1; off < 256; off <<= 1) {
        int v = (t >= off) ? part[t - off] : 0;
        __syncthreads();
        part[t] += v;
        __syncthreads();
    }
    int run = (t == 0) ? 0 : part[t - 1];
    for (int i = 0; i < 80; ++i) {
        int n = start + i;
        if (n < NN) { base[n] = run; cursor[n] = run; run += deg[n]; }
    }
    if (t == 255) base[NN] = run;   // == NE
}

__global__ __launch_bounds__(256) void k_fill(const int* __restrict__ ei,
                                              int* __restrict__ cursor,
                                              int* __restrict__ eidx)
{
    int e = blockIdx.x * 256 + threadIdx.x;
    int slot = atomicAdd(&cursor[ei[NE + e]], 1);
    eidx[slot] = e;
}

// -------- per-edge message kernel (chunked CSR path): writes msg[(slot-c0)*128..] --------
__global__ __launch_bounds__(256) void k_edge_msg(const float* __restrict__ coords,
                                                  const int* __restrict__ ei,
                                                  const int* __restrict__ eidx,
                                                  const float* __restrict__ W1,
                                                  const float* __restrict__ b1,
                                                  const float* __restrict__ W2,
                                                  const float* __restrict__ s_cur,
                                                  const float* __restrict__ v_cur,
                                                  float* __restrict__ msg,
                                                  int c0, int c1)
{
    __shared__ float w2s[64 * 160];             // 40 KB
    {
        const float4* src = reinterpret_cast<const float4*>(W2);
        float4* dst = reinterpret_cast<float4*>(w2s);
        #pragma unroll
        for (int i = 0; i < 10; ++i) dst[threadIdx.x + 256 * i] = src[threadIdx.x + 256 * i];
    }
    __syncthreads();

    int slot = c0 + blockIdx.x * 256 + threadIdx.x;
    if (slot >= c1) return;
    int e = eidx[slot];
    int snd = ei[e], rcv = ei[NE + e];

    float d0 = coords[snd * 3 + 0] - coords[rcv * 3 + 0];
    float d1 = coords[snd * 3 + 1] - coords[rcv * 3 + 1];
    float d2 = coords[snd * 3 + 2] - coords[rcv * 3 + 2];
    float r2 = d0 * d0 + d1 * d1 + d2 * d2 + 1e-12f;
    float r = sqrtf(r2);
    float rinv = 1.0f / r;
    float Y0 = SQRT3 * d0 * rinv, Y1 = SQRT3 * d1 * rinv, Y2 = SQRT3 * d2 * rinv;
    float x = r * 0.2f;                          // r / RMAX

    float x2 = x * x, x3 = x2 * x, x6 = x3 * x3;
    float fc = 1.0f + x6 * (-28.0f + x * (48.0f - 21.0f * x));
    fc = (x < 1.0f) ? fc : 0.0f;
    float scale = BPREF * rinv * fc;

    float s1, c1s;
    __sincosf(PI_F * x, &s1, &c1s);
    float ef[8];
    float sp = 0.f, sc = s1, twoc = 2.f * c1s;
    ef[0] = sc * scale;
    #pragma unroll
    for (int n = 1; n < 8; ++n) { float nx = twoc * sc - sp; sp = sc; sc = nx; ef[n] = sc * scale; }

    float h[64];
    #pragma unroll
    for (int j = 0; j < 64; ++j) {
        float acc = b1[j];
        #pragma unroll
        for (int b = 0; b < 8; ++b) acc += ef[b] * W1[b * 64 + j];
        h[j] = acc * sigmoidf_(acc);
    }

    const float* srow = s_cur + snd * 32;
    const float* vrow = v_cur + snd * 96;
    float* mout = msg + (size_t)(slot - c0) * 128;

    for (int f0 = 0; f0 < 32; f0 += 4) {
        float acc[5][4];
        #pragma unroll
        for (int p = 0; p < 5; ++p) { acc[p][0] = 0.f; acc[p][1] = 0.f; acc[p][2] = 0.f; acc[p][3] = 0.f; }
        #pragma unroll
        for (int j = 0; j < 64; ++j) {
            float hj = h[j];
            #pragma unroll
            for (int p = 0; p < 5; ++p) {
                const float4 wv = *reinterpret_cast<const float4*>(&w2s[j * 160 + p * 32 + f0]);
                acc[p][0] += hj * wv.x; acc[p][1] += hj * wv.y;
                acc[p][2] += hj * wv.z; acc[p][3] += hj * wv.w;
            }
        }
        float ms[4], mv[12];
        #pragma unroll
        for (int i = 0; i < 4; ++i) {
            int f = f0 + i;
            float sj = srow[f];
            float v0 = vrow[f * 3 + 0], v1 = vrow[f * 3 + 1], v2 = vrow[f * 3 + 2];
            float dot = v0 * Y0 + v1 * Y1 + v2 * Y2;
            float cr0 = v1 * Y2 - v2 * Y1;
            float cr1 = v2 * Y0 - v0 * Y2;
            float cr2 = v0 * Y1 - v1 * Y0;
            ms[i]        = acc[0][i] * sj + acc[3][i] * dot;
            float t1     = acc[1][i] * sj;
            mv[i * 3 + 0] = t1 * Y0 + acc[2][i] * v0 + acc[4][i] * cr0;
            mv[i * 3 + 1] = t1 * Y1 + acc[2][i] * v1 + acc[4][i] * cr1;
            mv[i * 3 + 2] = t1 * Y2 + acc[2][i] * v2 + acc[4][i] * cr2;
        }
        *reinterpret_cast<float4*>(mout + f0) = make_float4(ms[0], ms[1], ms[2], ms[3]);
        float4* vv = reinterpret_cast<float4*>(mout + 32 + f0 * 3);
        vv[0] = make_float4(mv[0], mv[1], mv[2], mv[3]);
        vv[1] = make_float4(mv[4], mv[5], mv[6], mv[7]);
        vv[2] = make_float4(mv[8], mv[9], mv[10], mv[11]);
    }
}

// -------- chunked segment-sum gather: agg += partial over [c0,c1) --------
__global__ __launch_bounds__(256) void k_gather(const float* __restrict__ msg,
                                                const int* __restrict__ base,
                                                float* __restrict__ agg_s,
                                                float* __restrict__ agg_v,
                                                int c0, int c1)
{
    int t = threadIdx.x & 127;
    int n = (blockIdx.x << 1) | (threadIdx.x >> 7);
    if (n >= NN) return;
    int b0 = base[n], b1 = base[n + 1];
    int lo = b0 > c0 ? b0 : c0;
    int hi = b1 < c1 ? b1 : c1;
    if (lo >= hi) return;
    float acc = 0.f;
    for (int i = lo; i < hi; ++i) acc += msg[(size_t)(i - c0) * 128 + t];
    acc *= INV_AVG;
    if (t < 32) agg_s[n * 32 + t] += acc;
    else        agg_v[n * 96 + (t - 32)] += acc;
}

// ---------------- fused node update (s + gate + v) ----------------
// grid = 313 tiles x 2 g-halves; block 512 = 8 waves; wave owns 2 g's:
// g0 = ghalf*16 + wave*2. lane = node-in-tile (64 nodes/block).
// Weights wave-uniform -> s_load_dwordx2; attrs row register-resident.
// block<=512 keeps VGPR ceiling at 256 (round-6 lesson: block 1024 capped
// VGPR<=128 and spilled ar[] -> 1.47GB refetch). Grid 626*8 = 5008 waves
// (~4.9/SIMD at VGPR<=128) vs round-7's 2504 (grid-limited latency hiding).
__global__ __launch_bounds__(512) void k_node(const float* __restrict__ attrs,
                                              const float* __restrict__ s_cur,
                                              const float* __restrict__ v_cur,
                                              const float* __restrict__ agg_s,
                                              const float* __restrict__ agg_v,
                                              const float* __restrict__ scWs,
                                              const float* __restrict__ linWs,
                                              const float* __restrict__ scWv,
                                              const float* __restrict__ linWv,
                                              float* __restrict__ s_next,
                                              float* __restrict__ v_next)
{
    int wave  = threadIdx.x >> 6;                // 0..7
    int l     = threadIdx.x & 63;
    int tile  = blockIdx.x >> 1;
    int ghalf = blockIdx.x & 1;
    int g0    = __builtin_amdgcn_readfirstlane(ghalf * 16 + wave * 2);  // 0..30, even
    int n     = tile * 64 + l;
    int nc    = (n < NN) ? n : (NN - 1);

    // attrs row -> 64 VGPRs (static indexing only)
    float ar[64];
    #pragma unroll
    for (int i = 0; i < 16; ++i) {
        const float4 v = *reinterpret_cast<const float4*>(&attrs[nc * 64 + i * 4]);
        ar[i * 4 + 0] = v.x; ar[i * 4 + 1] = v.y; ar[i * 4 + 2] = v.z; ar[i * 4 + 3] = v.w;
    }

    float sl0 = 0.f, sl1 = 0.f;      // pre_s feats  g0, g0+1
    float sh0 = 0.f, sh1 = 0.f;      // pre_s gates  g0+32, g0+33
    float va[2][3] = {};             // pre_v [g-offset][component]

    const float* sr = s_cur + (size_t)nc * 32;
    const float* vr = v_cur + (size_t)nc * 96;
    for (int f = 0; f < 32; ++f) {
        float sf = sr[f];
        float v0 = vr[f * 3 + 0], v1 = vr[f * 3 + 1], v2 = vr[f * 3 + 2];
        const float* wrow_s = scWs + ((size_t)f * 64) * 64;
        const float* wrow_v = scWv + ((size_t)f * 64) * 32;
        #pragma unroll
        for (int a = 0; a < 64; ++a) {
            float at = ar[a];
            float o  = sf * at;
            float p0 = at * v0, p1 = at * v1, p2 = at * v2;
            const float2 wl = *reinterpret_cast<const float2*>(wrow_s + a * 64 + g0);
            const float2 wh = *reinterpret_cast<const float2*>(wrow_s + a * 64 + g0 + 32);
            const float2 wv = *reinterpret_cast<const float2*>(wrow_v + a * 32 + g0);
            sl0 += o * wl.x; sl1 += o * wl.y;
            sh0 += o * wh.x; sh1 += o * wh.y;
            va[0][0] += p0 * wv.x; va[0][1] += p1 * wv.x; va[0][2] += p2 * wv.x;
            va[1][0] += p0 * wv.y; va[1][1] += p1 * wv.y; va[1][2] += p2 * wv.y;
        }
    }
    // linear parts on agg_s / agg_v
    const float* gs = agg_s + (size_t)nc * 32;
    const float* gv = agg_v + (size_t)nc * 96;
    #pragma unroll
    for (int f = 0; f < 32; ++f) {
        float av = gs[f];
        float q0 = gv[f * 3 + 0], q1 = gv[f * 3 + 1], q2 = gv[f * 3 + 2];
        const float2 wl = *reinterpret_cast<const float2*>(linWs + f * 64 + g0);
        const float2 wh = *reinterpret_cast<const float2*>(linWs + f * 64 + g0 + 32);
        const float2 wv = *reinterpret_cast<const float2*>(linWv + f * 32 + g0);
        sl0 += av * wl.x; sl1 += av * wl.y;
        sh0 += av * wh.x; sh1 += av * wh.y;
        va[0][0] += q0 * wv.x; va[0][1] += q1 * wv.x; va[0][2] += q2 * wv.x;
        va[1][0] += q0 * wv.y; va[1][1] += q1 * wv.y; va[1][2] += q2 * wv.y;
    }

    if (n < NN) {
        float pres[2] = {sl0, sl1};
        float preg[2] = {sh0, sh1};
        #pragma unroll
        for (int j = 0; j < 2; ++j) {
            int g = g0 + j;
            float pre = pres[j];
            s_next[n * 32 + g] = pre * sigmoidf_(pre) + s_cur[n * 32 + g];
            float gt = sigmoidf_(preg[j]);
            #pragma unroll
            for (int c = 0; c < 3; ++c) {
                int idx = (n * 32 + g) * 3 + c;
                v_next[idx] = va[j][c] * gt + v_cur[idx];
            }
        }
    }
}

__global__ __launch_bounds__(256) void k_out(const float* __restrict__ s,
                                             const float* __restrict__ v,
                                             float* __restrict__ out)
{
    int t = blockIdx.x * 256 + threadIdx.x;      // t < NN*128
    int n = t >> 7, i = t & 127;
    float val = (i < 32) ? s[n * 32 + i] : v[n * 96 + (i - 32)];
    out[t] = val;
}

extern "C" void kernel_launch(void* const* d_in, const int* in_sizes, int n_in,
                              void* d_out, int out_size, void* d_ws, size_t ws_size,
                              hipStream_t stream)
{
    const float* attrs  = (const float*)d_in[0];
    const float* coords = (const float*)d_in[1];
    const int*   ei     = (const int*)d_in[2];
    const float* embW   = (const float*)d_in[3];
    const float* radW1  = (const float*)d_in[4];
    const float* radb1  = (const float*)d_in[5];
    const float* radW2  = (const float*)d_in[6];
    const float* linWs  = (const float*)d_in[7];
    const float* linWv  = (const float*)d_in[8];
    const float* scWs   = (const float*)d_in[9];
    const float* scWv   = (const float*)d_in[10];
    float* out = (float*)d_out;

    float* ws = (float*)d_ws;
    const size_t NS = (size_t)NN * 32, NV = (size_t)NN * 96;
    float* s_a   = ws;
    float* s_b   = s_a + NS;
    float* v_a   = s_b + NS;
    float* v_b   = v_a + NV;
    float* agg_s = v_b + NV;
    float* agg_v = agg_s + NS;   // contiguous with agg_s -> single memset
    float* gate  = agg_v + NV;   // (unused since fusion; layout kept)
    int*   ip    = (int*)(gate + NS);
    int*   deg    = ip;
    int*   basep  = deg + NN;                  // NN+1 entries
    int*   cursor = basep + NN + 1;
    int*   eidx   = cursor + NN;
    float* msg   = (float*)(ip + 700004);      // 16B-aligned chunk slab

    // Largest chunk of edges whose 128-float messages fit in remaining ws.
    const size_t fixedBytes = (size_t)((char*)msg - (char*)ws);
    size_t avail = (ws_size > fixedBytes) ? (ws_size - fixedBytes) : 0;
    long long cap = (long long)(avail / (128 * sizeof(float)));
    int C = (int)(cap > NE ? NE : cap);
    C &= ~255;                                  // multiple of 256
    const bool use_csr = (C >= 256);

    hipMemsetAsync(v_a, 0, NV * sizeof(float), stream);
    k_embed<<<2500, 256, 0, stream>>>(attrs, embW, s_a);

    if (use_csr) {
        hipMemsetAsync(deg, 0, NN * sizeof(int), stream);
        k_count<<<NE / 256, 256, 0, stream>>>(ei, deg);
        k_scan<<<1, 256, 0, stream>>>(deg, basep, cursor);
        k_fill<<<NE / 256, 256, 0, stream>>>(ei, cursor, eidx);
    }

    float* scur = s_a; float* snext = s_b;
    float* vcur = v_a; float* vnext = v_b;
    for (int l = 0; l < 2; ++l) {
        hipMemsetAsync(agg_s, 0, (NS + NV) * sizeof(float), stream);
        if (use_csr) {
            for (int c0 = 0; c0 < NE; c0 += C) {
                int c1 = (c0 + C < NE) ? (c0 + C) : NE;
                int len = c1 - c0;
                k_edge_msg<<<(len + 255) / 256, 256, 0, stream>>>(coords, ei, eidx,
                    radW1 + l * 8 * 64, radb1 + l * 64, radW2 + l * 64 * 160,
                    scur, vcur, msg, c0, c1);
                k_gather<<<NN / 2, 256, 0, stream>>>(msg, basep, agg_s, agg_v, c0, c1);
            }
        }
        k_node<<<626, 512, 0, stream>>>(attrs, scur, vcur, agg_s, agg_v,
            scWs + l * 32 * 64 * 64, linWs + l * 32 * 64,
            scWv + l * 32 * 64 * 32, linWv + l * 32 * 32,
            snext, vnext);
        float* tt = scur; scur = snext; snext = tt;
        tt = vcur; vcur = vnext; vnext = tt;
    }
    k_out<<<10000, 256, 0, stream>>>(scur, vcur, out);
}

// Round 13
// 2219.326 us; speedup vs baseline: 1.8302x; 1.8302x over previous
//
#include <hip/hip_runtime.h>
#include <hip/hip_bf16.h>

#define NN 20000
#define NE 640000

constexpr float INV_AVG = 0.17677669529663687f;  // 1/sqrt(32)
constexpr float SQRT3   = 1.7320508075688772f;
constexpr float BPREF   = 0.6324555320336759f;   // sqrt(2/5)
constexpr float PI_F    = 3.14159265358979323846f;

__device__ __forceinline__ float sigmoidf_(float x) { return 1.0f / (1.0f + __expf(-x)); }

// ---------------- embedding ----------------
__global__ __launch_bounds__(256) void k_embed(const float* __restrict__ attrs,
                                               const float* __restrict__ W,
                                               float* __restrict__ s)
{
    int t = blockIdx.x * 256 + threadIdx.x;     // t = n*32 + f
    int n = t >> 5, f = t & 31;
    const float* ar = attrs + n * 64;
    float acc = 0.f;
    #pragma unroll
    for (int a = 0; a < 64; ++a) acc += ar[a] * W[a * 32 + f];
    s[t] = acc;
}

// ---------------- CSR build ----------------
__global__ __launch_bounds__(256) void k_count(const int* __restrict__ ei, int* __restrict__ deg)
{
    int e = blockIdx.x * 256 + threadIdx.x;
    atomicAdd(&deg[ei[NE + e]], 1);
}

__global__ __launch_bounds__(256) void k_scan(const int* __restrict__ deg,
                                              int* __restrict__ base,
                                              int* __restrict__ cursor)
{
    __shared__ int part[256];
    int t = threadIdx.x;
    int start = t * 80;
    int s = 0;
    for (int i = 0; i < 80; ++i) { int n = start + i; if (n < NN) s += deg[n]; }
    part[t] = s;
    __syncthreads();
    for (int off = 1; off < 256; off <<= 1) {
        int v = (t >= off) ? part[t - off] : 0;
        __syncthreads();
        part[t] += v;
        __syncthreads();
    }
    int run = (t == 0) ? 0 : part[t - 1];
    for (int i = 0; i < 80; ++i) {
        int n = start + i;
        if (n < NN) { base[n] = run; cursor[n] = run; run += deg[n]; }
    }
    if (t == 255) base[NN] = run;   // == NE
}

__global__ __launch_bounds__(256) void k_fill(const int* __restrict__ ei,
                                              int* __restrict__ cursor,
                                              int* __restrict__ eidx)
{
    int e = blockIdx.x * 256 + threadIdx.x;
    int slot = atomicAdd(&cursor[ei[NE + e]], 1);
    eidx[slot] = e;
}

// -------- fused edge kernel: message compute + in-block segmented reduction --------
// Grid = NE/256 = 2500 exact. Block = 256 (4 waves). Slot range [s0, s0+256).
// CSR: slots of a node are contiguous -> runs of equal rcv within the block.
// Per 16-float chunk: write col-major LDS red[16][257] (pad -> conflict-free),
// then (run, col) workers serially sum and write agg: plain store if node's whole
// segment is inside this block, else unsafeAtomicAdd (boundary runs, ~2/block).
__global__ __launch_bounds__(256) void k_edge_red(const float* __restrict__ coords,
                                                  const int* __restrict__ ei,
                                                  const int* __restrict__ eidx,
                                                  const int* __restrict__ basep,
                                                  const float* __restrict__ W1,
                                                  const float* __restrict__ b1,
                                                  const float* __restrict__ W2,
                                                  const float* __restrict__ s_cur,
                                                  const float* __restrict__ v_cur,
                                                  float* __restrict__ agg_s,
                                                  float* __restrict__ agg_v)
{
    __shared__ float w2s[64 * 160];             // 40 KB
    __shared__ float red[16 * 257];             // 16.4 KB, red[c*257 + slot]
    __shared__ int   rcvs[256];
    __shared__ int   runStart[257];
    __shared__ int   runCnt;

    int t = threadIdx.x;
    {
        const float4* src = reinterpret_cast<const float4*>(W2);
        float4* dst = reinterpret_cast<float4*>(w2s);
        #pragma unroll
        for (int i = 0; i < 10; ++i) dst[t + 256 * i] = src[t + 256 * i];
    }
    if (t == 0) runCnt = 0;

    int s0 = blockIdx.x * 256;
    int slot = s0 + t;
    int e = eidx[slot];
    int snd = ei[e], rcv = ei[NE + e];
    rcvs[t] = rcv;
    __syncthreads();                            // w2s, rcvs, runCnt=0 visible

    if (t == 0 || rcvs[t] != rcvs[t - 1]) {
        int idx = atomicAdd(&runCnt, 1);
        runStart[idx] = t;
    }
    // (visibility of runStart/runCnt guaranteed by the pre-write sync in chunk 0)

    float d0 = coords[snd * 3 + 0] - coords[rcv * 3 + 0];
    float d1 = coords[snd * 3 + 1] - coords[rcv * 3 + 1];
    float d2 = coords[snd * 3 + 2] - coords[rcv * 3 + 2];
    float r2 = d0 * d0 + d1 * d1 + d2 * d2 + 1e-12f;
    float r = sqrtf(r2);
    float rinv = 1.0f / r;
    float Y0 = SQRT3 * d0 * rinv, Y1 = SQRT3 * d1 * rinv, Y2 = SQRT3 * d2 * rinv;
    float x = r * 0.2f;                          // r / RMAX

    float x2 = x * x, x3 = x2 * x, x6 = x3 * x3;
    float fc = 1.0f + x6 * (-28.0f + x * (48.0f - 21.0f * x));
    fc = (x < 1.0f) ? fc : 0.0f;
    float scale = BPREF * rinv * fc;

    float s1, c1s;
    __sincosf(PI_F * x, &s1, &c1s);
    float ef[8];
    float sp = 0.f, sc = s1, twoc = 2.f * c1s;
    ef[0] = sc * scale;
    #pragma unroll
    for (int n = 1; n < 8; ++n) { float nx = twoc * sc - sp; sp = sc; sc = nx; ef[n] = sc * scale; }

    float h[64];
    #pragma unroll
    for (int j = 0; j < 64; ++j) {
        float acc = b1[j];
        #pragma unroll
        for (int b = 0; b < 8; ++b) acc += ef[b] * W1[b * 64 + j];
        h[j] = acc * sigmoidf_(acc);
    }

    const float* srow = s_cur + snd * 32;
    const float* vrow = v_cur + snd * 96;

    for (int f0 = 0; f0 < 32; f0 += 4) {
        float acc[5][4];
        #pragma unroll
        for (int p = 0; p < 5; ++p) { acc[p][0] = 0.f; acc[p][1] = 0.f; acc[p][2] = 0.f; acc[p][3] = 0.f; }
        #pragma unroll
        for (int j = 0; j < 64; ++j) {
            float hj = h[j];
            #pragma unroll
            for (int p = 0; p < 5; ++p) {
                const float4 wv = *reinterpret_cast<const float4*>(&w2s[j * 160 + p * 32 + f0]);
                acc[p][0] += hj * wv.x; acc[p][1] += hj * wv.y;
                acc[p][2] += hj * wv.z; acc[p][3] += hj * wv.w;
            }
        }
        __syncthreads();                         // previous chunk's reduce done
        #pragma unroll
        for (int i = 0; i < 4; ++i) {
            int f = f0 + i;
            float sj = srow[f];
            float v0 = vrow[f * 3 + 0], v1 = vrow[f * 3 + 1], v2 = vrow[f * 3 + 2];
            float dot = v0 * Y0 + v1 * Y1 + v2 * Y2;
            float cr0 = v1 * Y2 - v2 * Y1;
            float cr1 = v2 * Y0 - v0 * Y2;
            float cr2 = v0 * Y1 - v1 * Y0;
            red[i * 257 + t]            = acc[0][i] * sj + acc[3][i] * dot;
            float t1                    = acc[1][i] * sj;
            red[(4 + i * 3 + 0) * 257 + t] = t1 * Y0 + acc[2][i] * v0 + acc[4][i] * cr0;
            red[(4 + i * 3 + 1) * 257 + t] = t1 * Y1 + acc[2][i] * v1 + acc[4][i] * cr1;
            red[(4 + i * 3 + 2) * 257 + t] = t1 * Y2 + acc[2][i] * v2 + acc[4][i] * cr2;
        }
        __syncthreads();                         // red ready
        int nr = runCnt;
        int c = t & 15;
        for (int rr = t >> 4; rr < nr; rr += 16) {
            int rs = runStart[rr];
            int n = rcvs[rs];
            int re = rs + 1;
            while (re < 256 && rcvs[re] == n) ++re;
            float sum = 0.f;
            for (int i2 = rs; i2 < re; ++i2) sum += red[c * 257 + i2];
            sum *= INV_AVG;
            int gb0 = basep[n], gb1 = basep[n + 1];
            bool complete = (gb0 >= s0) && (gb1 <= s0 + 256);
            float* dst;
            if (c < 4) dst = &agg_s[n * 32 + f0 + c];
            else { int j = c - 4; dst = &agg_v[n * 96 + (f0 + j / 3) * 3 + (j % 3)]; }
            if (complete) *dst = sum;
            else unsafeAtomicAdd(dst, sum);
        }
    }
}

// -------- atomic fallback edge kernel (only if ws too small for CSR arrays) --------
__global__ __launch_bounds__(256) void k_edge(const float* __restrict__ coords,
                                              const int* __restrict__ ei,
                                              const float* __restrict__ W1,
                                              const float* __restrict__ b1,
                                              const float* __restrict__ W2,
                                              const float* __restrict__ s_cur,
                                              const float* __restrict__ v_cur,
                                              float* __restrict__ agg_s,
                                              float* __restrict__ agg_v)
{
    __shared__ float w2s[64 * 160];
    {
        const float4* src = reinterpret_cast<const float4*>(W2);
        float4* dst = reinterpret_cast<float4*>(w2s);
        #pragma unroll
        for (int i = 0; i < 10; ++i) dst[threadIdx.x + 256 * i] = src[threadIdx.x + 256 * i];
    }
    __syncthreads();

    int e = blockIdx.x * 256 + threadIdx.x;
    int snd = ei[e], rcv = ei[NE + e];

    float d0 = coords[snd * 3 + 0] - coords[rcv * 3 + 0];
    float d1 = coords[snd * 3 + 1] - coords[rcv * 3 + 1];
    float d2 = coords[snd * 3 + 2] - coords[rcv * 3 + 2];
    float r2 = d0 * d0 + d1 * d1 + d2 * d2 + 1e-12f;
    float r = sqrtf(r2);
    float rinv = 1.0f / r;
    float Y0 = SQRT3 * d0 * rinv, Y1 = SQRT3 * d1 * rinv, Y2 = SQRT3 * d2 * rinv;
    float x = r * 0.2f;

    float x2 = x * x, x3 = x2 * x, x6 = x3 * x3;
    float fc = 1.0f + x6 * (-28.0f + x * (48.0f - 21.0f * x));
    fc = (x < 1.0f) ? fc : 0.0f;
    float scale = BPREF * rinv * fc;

    float s1, c1;
    __sincosf(PI_F * x, &s1, &c1);
    float ef[8];
    float sp = 0.f, sc = s1, twoc = 2.f * c1;
    ef[0] = sc * scale;
    #pragma unroll
    for (int n = 1; n < 8; ++n) { float nx = twoc * sc - sp; sp = sc; sc = nx; ef[n] = sc * scale; }

    float h[64];
    #pragma unroll
    for (int j = 0; j < 64; ++j) {
        float acc = b1[j];
        #pragma unroll
        for (int b = 0; b < 8; ++b) acc += ef[b] * W1[b * 64 + j];
        h[j] = acc * sigmoidf_(acc);
    }

    const float* srow = s_cur + snd * 32;
    const float* vrow = v_cur + snd * 96;
    float* as = agg_s + rcv * 32;
    float* av = agg_v + rcv * 96;

    for (int f0 = 0; f0 < 32; f0 += 4) {
        float acc[5][4];
        #pragma unroll
        for (int p = 0; p < 5; ++p) { acc[p][0] = 0.f; acc[p][1] = 0.f; acc[p][2] = 0.f; acc[p][3] = 0.f; }
        #pragma unroll
        for (int j = 0; j < 64; ++j) {
            float hj = h[j];
            #pragma unroll
            for (int p = 0; p < 5; ++p) {
                const float4 wv = *reinterpret_cast<const float4*>(&w2s[j * 160 + p * 32 + f0]);
                acc[p][0] += hj * wv.x; acc[p][1] += hj * wv.y;
                acc[p][2] += hj * wv.z; acc[p][3] += hj * wv.w;
            }
        }
        #pragma unroll
        for (int i = 0; i < 4; ++i) {
            int f = f0 + i;
            float sj = srow[f];
            float v0 = vrow[f * 3 + 0], v1 = vrow[f * 3 + 1], v2 = vrow[f * 3 + 2];
            float dot = v0 * Y0 + v1 * Y1 + v2 * Y2;
            float cr0 = v1 * Y2 - v2 * Y1;
            float cr1 = v2 * Y0 - v0 * Y2;
            float cr2 = v0 * Y1 - v1 * Y0;
            float ms  = (acc[0][i] * sj + acc[3][i] * dot) * INV_AVG;
            float t1  = acc[1][i] * sj;
            float mv0 = (t1 * Y0 + acc[2][i] * v0 + acc[4][i] * cr0) * INV_AVG;
            float mv1 = (t1 * Y1 + acc[2][i] * v1 + acc[4][i] * cr1) * INV_AVG;
            float mv2 = (t1 * Y2 + acc[2][i] * v2 + acc[4][i] * cr2) * INV_AVG;
            unsafeAtomicAdd(as + f, ms);
            unsafeAtomicAdd(av + f * 3 + 0, mv0);
            unsafeAtomicAdd(av + f * 3 + 1, mv1);
            unsafeAtomicAdd(av + f * 3 + 2, mv2);
        }
    }
}

// ---------------- node update: scalar path (round-7 proven) ----------------
// block 512 = 8 waves; wave w owns g-slices [4w,4w+4) and [4w+32,4w+36); lane = node.
// Single-kernel = 2 wide float4 s_load streams per 16 VALU (round-12 lesson: the
// 3-stream float2 fused variant is s_load-latency-bound at 14.8% VALUBusy).
__global__ __launch_bounds__(512) void k_node_s(const float* __restrict__ attrs,
                                                const float* __restrict__ s_cur,
                                                const float* __restrict__ agg_s,
                                                const float* __restrict__ scWs,
                                                const float* __restrict__ linWs,
                                                float* __restrict__ s_next,
                                                float* __restrict__ gate)
{
    int wave = threadIdx.x >> 6;                 // 0..7
    int l    = threadIdx.x & 63;
    int g0   = __builtin_amdgcn_readfirstlane(wave * 4);   // 0..28
    int n    = blockIdx.x * 64 + l;
    int nc   = (n < NN) ? n : (NN - 1);

    float ar[64];
    #pragma unroll
    for (int i = 0; i < 16; ++i) {
        const float4 v = *reinterpret_cast<const float4*>(&attrs[nc * 64 + i * 4]);
        ar[i * 4 + 0] = v.x; ar[i * 4 + 1] = v.y; ar[i * 4 + 2] = v.z; ar[i * 4 + 3] = v.w;
    }

    float lo0 = 0.f, lo1 = 0.f, lo2 = 0.f, lo3 = 0.f;   // g = g0..g0+3   (feats)
    float hi0 = 0.f, hi1 = 0.f, hi2 = 0.f, hi3 = 0.f;   // g = g0+32..+35 (gates)
    const float* sr = s_cur + (size_t)nc * 32;
    for (int f = 0; f < 32; ++f) {
        float sf = sr[f];
        const float* wrow = scWs + ((size_t)f * 64) * 64;
        #pragma unroll
        for (int a = 0; a < 64; ++a) {
            float o = sf * ar[a];
            const float4 wl = *reinterpret_cast<const float4*>(wrow + a * 64 + g0);
            const float4 wh = *reinterpret_cast<const float4*>(wrow + a * 64 + g0 + 32);
            lo0 += o * wl.x; lo1 += o * wl.y; lo2 += o * wl.z; lo3 += o * wl.w;
            hi0 += o * wh.x; hi1 += o * wh.y; hi2 += o * wh.z; hi3 += o * wh.w;
        }
    }
    const float* gr = agg_s + (size_t)nc * 32;
    #pragma unroll
    for (int f = 0; f < 32; ++f) {
        float av = gr[f];
        const float4 wl = *reinterpret_cast<const float4*>(linWs + f * 64 + g0);
        const float4 wh = *reinterpret_cast<const float4*>(linWs + f * 64 + g0 + 32);
        lo0 += av * wl.x; lo1 += av * wl.y; lo2 += av * wl.z; lo3 += av * wl.w;
        hi0 += av * wh.x; hi1 += av * wh.y; hi2 += av * wh.z; hi3 += av * wh.w;
    }

    if (n < NN) {
        float los[4] = {lo0, lo1, lo2, lo3};
        float his[4] = {hi0, hi1, hi2, hi3};
        #pragma unroll
        for (int j = 0; j < 4; ++j) {
            int g = g0 + j;
            float pre = los[j];
            s_next[n * 32 + g] = pre * sigmoidf_(pre) + s_cur[n * 32 + g];
            gate[n * 32 + g]   = sigmoidf_(his[j]);
        }
    }
}

__global__ __launch_bounds__(512) void k_node_v(const float* __restrict__ attrs,
                                                const float* __restrict__ v_cur,
                                                const float* __restrict__ agg_v,
                                                const float* __restrict__ scWv,
                                                const float* __restrict__ linWv,
                                                const float* __restrict__ gate,
                                                float* __restrict__ v_next)
{
    int wave = threadIdx.x >> 6;                 // 0..7
    int l    = threadIdx.x & 63;
    int g0   = __builtin_amdgcn_readfirstlane(wave * 4);   // 0..28
    int n    = blockIdx.x * 64 + l;
    int nc   = (n < NN) ? n : (NN - 1);

    float ar[64];
    #pragma unroll
    for (int i = 0; i < 16; ++i) {
        const float4 v = *reinterpret_cast<const float4*>(&attrs[nc * 64 + i * 4]);
        ar[i * 4 + 0] = v.x; ar[i * 4 + 1] = v.y; ar[i * 4 + 2] = v.z; ar[i * 4 + 3] = v.w;
    }

    float acc[4][3] = {};                        // [g-offset][component]
    const float* vr = v_cur + (size_t)nc * 96;
    for (int f = 0; f < 32; ++f) {
        float v0 = vr[f * 3 + 0], v1 = vr[f * 3 + 1], v2 = vr[f * 3 + 2];
        const float* wrow = scWv + ((size_t)f * 64) * 32 + g0;
        #pragma unroll
        for (int a = 0; a < 64; ++a) {
            const float4 wv = *reinterpret_cast<const float4*>(wrow + a * 32);
            float at = ar[a];
            float o0 = at * v0, o1 = at * v1, o2 = at * v2;
            acc[0][0] += o0 * wv.x; acc[0][1] += o1 * wv.x; acc[0][2] += o2 * wv.x;
            acc[1][0] += o0 * wv.y; acc[1][1] += o1 * wv.y; acc[1][2] += o2 * wv.y;
            acc[2][0] += o0 * wv.z; acc[2][1] += o1 * wv.z; acc[2][2] += o2 * wv.z;
            acc[3][0] += o0 * wv.w; acc[3][1] += o1 * wv.w; acc[3][2] += o2 * wv.w;
        }
    }
    const float* gr = agg_v + (size_t)nc * 96;
    #pragma unroll
    for (int f = 0; f < 32; ++f) {
        float q0 = gr[f * 3 + 0], q1 = gr[f * 3 + 1], q2 = gr[f * 3 + 2];
        const float4 wv = *reinterpret_cast<const float4*>(linWv + f * 32 + g0);
        acc[0][0] += q0 * wv.x; acc[0][1] += q1 * wv.x; acc[0][2] += q2 * wv.x;
        acc[1][0] += q0 * wv.y; acc[1][1] += q1 * wv.y; acc[1][2] += q2 * wv.y;
        acc[2][0] += q0 * wv.z; acc[2][1] += q1 * wv.z; acc[2][2] += q2 * wv.z;
        acc[3][0] += q0 * wv.w; acc[3][1] += q1 * wv.w; acc[3][2] += q2 * wv.w;
    }

    if (n < NN) {
        #pragma unroll
        for (int j = 0; j < 4; ++j) {
            int g = g0 + j;
            float gt = gate[n * 32 + g];
            #pragma unroll
            for (int c = 0; c < 3; ++c) {
                int idx = (n * 32 + g) * 3 + c;
                v_next[idx] = acc[j][c] * gt + v_cur[idx];
            }
        }
    }
}

__global__ __launch_bounds__(256) void k_out(const float* __restrict__ s,
                                             const float* __restrict__ v,
                                             float* __restrict__ out)
{
    int t = blockIdx.x * 256 + threadIdx.x;      // t < NN*128
    int n = t >> 7, i = t & 127;
    float val = (i < 32) ? s[n * 32 + i] : v[n * 96 + (i - 32)];
    out[t] = val;
}

extern "C" void kernel_launch(void* const* d_in, const int* in_sizes, int n_in,
                              void* d_out, int out_size, void* d_ws, size_t ws_size,
                              hipStream_t stream)
{
    const float* attrs  = (const float*)d_in[0];
    const float* coords = (const float*)d_in[1];
    const int*   ei     = (const int*)d_in[2];
    const float* embW   = (const float*)d_in[3];
    const float* radW1  = (const float*)d_in[4];
    const float* radb1  = (const float*)d_in[5];
    const float* radW2  = (const float*)d_in[6];
    const float* linWs  = (const float*)d_in[7];
    const float* linWv  = (const float*)d_in[8];
    const float* scWs   = (const float*)d_in[9];
    const float* scWv   = (const float*)d_in[10];
    float* out = (float*)d_out;

    float* ws = (float*)d_ws;
    const size_t NS = (size_t)NN * 32, NV = (size_t)NN * 96;
    float* s_a   = ws;
    float* s_b   = s_a + NS;
    float* v_a   = s_b + NS;
    float* v_b   = v_a + NV;
    float* agg_s = v_b + NV;
    float* agg_v = agg_s + NS;   // contiguous with agg_s -> single memset
    float* gate  = agg_v + NV;
    int*   ip    = (int*)(gate + NS);
    int*   deg    = ip;
    int*   basep  = deg + NN;                  // NN+1 entries
    int*   cursor = basep + NN + 1;
    int*   eidx   = cursor + NN;               // NE entries

    const size_t required = (size_t)((char*)(eidx + NE) - (char*)ws);
    const bool use_csr = ws_size >= required;

    hipMemsetAsync(v_a, 0, NV * sizeof(float), stream);
    k_embed<<<2500, 256, 0, stream>>>(attrs, embW, s_a);

    if (use_csr) {
        hipMemsetAsync(deg, 0, NN * sizeof(int), stream);
        k_count<<<NE / 256, 256, 0, stream>>>(ei, deg);
        k_scan<<<1, 256, 0, stream>>>(deg, basep, cursor);
        k_fill<<<NE / 256, 256, 0, stream>>>(ei, cursor, eidx);
    }

    float* scur = s_a; float* snext = s_b;
    float* vcur = v_a; float* vnext = v_b;
    for (int l = 0; l < 2; ++l) {
        hipMemsetAsync(agg_s, 0, (NS + NV) * sizeof(float), stream);
        if (use_csr) {
            k_edge_red<<<NE / 256, 256, 0, stream>>>(coords, ei, eidx, basep,
                radW1 + l * 8 * 64, radb1 + l * 64, radW2 + l * 64 * 160,
                scur, vcur, agg_s, agg_v);
        } else {
            k_edge<<<NE / 256, 256, 0, stream>>>(coords, ei,
                radW1 + l * 8 * 64, radb1 + l * 64, radW2 + l * 64 * 160,
                scur, vcur, agg_s, agg_v);
        }
        k_node_s<<<313, 512, 0, stream>>>(attrs, scur, agg_s,
            scWs + l * 32 * 64 * 64, linWs + l * 32 * 64, snext, gate);
        k_node_v<<<313, 512, 0, stream>>>(attrs, vcur, agg_v,
            scWv + l * 32 * 64 * 32, linWv + l * 32 * 32, gate, vnext);
        float* tt = scur; scur = snext; snext = tt;
        tt = vcur; vcur = vnext; vnext = tt;
    }
    k_out<<<10000, 256, 0, stream>>>(scur, vcur, out);
}